// Round 5
// baseline (119.362 us; speedup 1.0000x reference)
//
#include <hip/hip_runtime.h>

// Conv2d 3x3 s1 p1, N=16 C=64 H=W=112 F=64, fp32 in/out, bf16 MFMA implicit GEMM.
// R9: fix the two stalls R8's counters exposed.
//  (1) VGPR_Count=152 proved the compiler rematerialized the 36 B-frags by
//      RELOADING them from global inside the tap loop (~51 TB/s L2 demand >
//      34.5 ceiling). Pin them with identity-asm ties -> truly load-free taps.
//  (2) Per-tile __syncthreads drained vmcnt(0) (stores + prefetch loads) 7x per
//      strip. Now: NPL=10 ring, pair-wise schedule -> stage writes target rows
//      oh+5..oh+8 which NO tile in the pair reads (10 consecutive live rows =
//      10 planes) -> one raw s_barrier + lgkmcnt(0) per 2 tiles; stores and
//      next loads fly across barriers (counted vmcnt, compiler-emitted).
//  Staging: 4-row rounds, all 8 waves participate. Pitch 67 keeps all LDS
//  access patterns bank-uniform. Direct float4 epilogue.

typedef __attribute__((ext_vector_type(8))) short bf16x8;
typedef __attribute__((ext_vector_type(4))) float f32x4;

#define CIN 64
#define COUT 64
#define HH 112
#define WW 112
#define NPL 10                    // ring planes (rows live: oh-1..oh+8)
#define WPITCH 67                 // wcol pitch: 16B-unit residue (3*oct+w)&7 uniform
#define PLANE_SHORTS (8 * WPITCH * 8)     // 4288 shorts = 8576 B
#define LDS_SHORTS (NPL * PLANE_SHORTS)   // 42880 shorts = 85760 B (1 block/CU)

__device__ __forceinline__ int pmod(int row) { return (row + NPL) % NPL; }  // row >= -1

__device__ __forceinline__ int ladr(int pl, int oct, int w) {
    // bf16 [plane][oct][wcol][8ch]; addr in shorts.
    return ((pl * 8 + oct) * WPITCH + w) * 8;
}

__device__ __forceinline__ unsigned short f2bf(float f) {
    unsigned u = __builtin_bit_cast(unsigned, f);
    u += 0x7FFFu + ((u >> 16) & 1u);   // round-to-nearest-even
    return (unsigned short)(u >> 16);
}

#if __has_builtin(__builtin_amdgcn_cvt_pk_bf16_f32)
__device__ __forceinline__ unsigned pk2bf(float a, float b) {
    typedef __attribute__((ext_vector_type(2))) __bf16 bf16x2;
    bf16x2 r = __builtin_amdgcn_cvt_pk_bf16_f32(a, b);
    return __builtin_bit_cast(unsigned, r);
}
#else
__device__ __forceinline__ unsigned pk2bf(float a, float b) {
    return (unsigned)f2bf(a) | ((unsigned)f2bf(b) << 16);
}
#endif

// lgkm-only barrier: ds_writes visible, vmcnt (stores/prefetch) stays in flight.
#define BAR_LGKM() do {                                   \
    __builtin_amdgcn_sched_barrier(0);                    \
    asm volatile("s_waitcnt lgkmcnt(0)" ::: "memory");    \
    __builtin_amdgcn_s_barrier();                         \
    __builtin_amdgcn_sched_barrier(0);                    \
} while (0)

// ---- one-time weight conversion: OIHW fp32 -> bf16 [t][cb][koct][f][j] ----
__global__ void conv_wprep(const float* __restrict__ w, short* __restrict__ wbf) {
    int i = blockIdx.x * 256 + threadIdx.x;    // grid sized to exactly 36864
    int j = i & 7;
    int f = (i >> 3) & 63;
    int koct = (i >> 9) & 3;
    int cb = (i >> 11) & 1;
    int t = i >> 12;
    int c = cb * 32 + koct * 8 + j;
    int ky = t / 3, kx = t - ky * 3;
    wbf[i] = (short)f2bf(w[((f * CIN + c) * 3 + ky) * 3 + kx]);
}

struct StageRegs {
    float4 v[8];   // interior unit: 8 channels x 4 cols
    float hv;      // halo-column value
};

// Issue global loads for an nr-row stage (rows row0..row0+nr-1) into regs.
// Unit: (re=tid>>7, oct, w4); halo: tid<64*nr; rows outside [0,HH) stay zero.
__device__ __forceinline__ void stage_load(const float* __restrict__ x, int tid,
                                           int n, int c0, int W4N, int gce,
                                           int row0, int nr, StageRegs& sr)
{
    const int re  = tid >> 7;
    const int oct = (tid >> 4) & 7;
    const int w4  = tid & 15;
    const int row = row0 + re;
#pragma unroll
    for (int k = 0; k < 8; ++k) sr.v[k] = (float4){0.f, 0.f, 0.f, 0.f};
    sr.hv = 0.f;
    if (re < nr && (unsigned)row < (unsigned)HH && w4 < W4N) {
        const float* px = x + (((n * CIN + oct * 8) * HH + row) * WW + c0 + w4 * 4);
#pragma unroll
        for (int k = 0; k < 8; ++k) sr.v[k] = *(const float4*)(px + k * HH * WW);
    }
    const int hr = tid >> 6;
    const int hrow = row0 + hr;
    if (hr < nr && (unsigned)hrow < (unsigned)HH)
        sr.hv = x[((n * CIN + (tid & 63)) * HH + hrow) * WW + gce];
}

// Convert + write staged regs into ring planes (zeros for out-of-range rows).
__device__ __forceinline__ void stage_write(short* lds, int tid, int W4N,
                                            int padw, int wedge, int row0,
                                            int nr, const StageRegs& sr)
{
    const int re  = tid >> 7;
    const int oct = (tid >> 4) & 7;
    const int w4  = tid & 15;
    if (re < nr && w4 < W4N) {
        const int pl = pmod(row0 + re);
        const float* fv = (const float*)&sr.v[0];
#pragma unroll
        for (int dw = 0; dw < 4; ++dw) {
            uint4 pk;
            pk.x = pk2bf(fv[0 * 4 + dw], fv[1 * 4 + dw]);
            pk.y = pk2bf(fv[2 * 4 + dw], fv[3 * 4 + dw]);
            pk.z = pk2bf(fv[4 * 4 + dw], fv[5 * 4 + dw]);
            pk.w = pk2bf(fv[6 * 4 + dw], fv[7 * 4 + dw]);
            *(uint4*)&lds[ladr(pl, oct, 1 + w4 * 4 + dw)] = pk;
        }
    }
    const int hr = tid >> 6;
    if (hr < nr) {
        const int pl = pmod(row0 + hr);
        const int c = tid & 63;
        lds[ladr(pl, c >> 3, wedge) + (c & 7)] = (short)f2bf(sr.hv);
    }
    if (tid < 8 * nr) {
        const int pl = pmod(row0 + (tid >> 3));
        *(uint4*)&lds[ladr(pl, tid & 7, padw)] = (uint4){0u, 0u, 0u, 0u};
    }
}

// One 2-row output tile: 9 taps x (2 mt) x 4 MFMA, then direct stores.
__device__ __forceinline__ void tile_compute(const short* lds,
    const bf16x8 (&bw)[9][2][2], float* __restrict__ out,
    int n, int c0, int MTN, int h0, int r, int nh, int mh, int lm, int q,
    float b0, float b1)
{
    f32x4 acc[2][2];
#pragma unroll
    for (int j = 0; j < 2; ++j)
#pragma unroll
        for (int ntl = 0; ntl < 2; ++ntl) acc[j][ntl] = (f32x4){0.f, 0.f, 0.f, 0.f};

    const int hro = h0 - 1 + r;
    int pls[3];
    pls[0] = pmod(hro); pls[1] = pmod(hro + 1); pls[2] = pmod(hro + 2);

#pragma unroll
    for (int tap = 0; tap < 9; ++tap) {
        const int ky = tap / 3, kx = tap - ky * 3;
        const int pl = pls[ky];               // ky is unroll-constant
#pragma unroll
        for (int j = 0; j < 2; ++j) {
            const int mt = mh * 2 + j;
            if (mt < MTN) {
                const int wcol = mt * 16 + lm + kx;
                const bf16x8 a0 = *(const bf16x8*)&lds[ladr(pl, q, wcol)];
                const bf16x8 a1 = *(const bf16x8*)&lds[ladr(pl, q + 4, wcol)];
                acc[j][0] = __builtin_amdgcn_mfma_f32_16x16x32_bf16(a0, bw[tap][0][0], acc[j][0], 0, 0, 0);
                acc[j][1] = __builtin_amdgcn_mfma_f32_16x16x32_bf16(a0, bw[tap][1][0], acc[j][1], 0, 0, 0);
                acc[j][0] = __builtin_amdgcn_mfma_f32_16x16x32_bf16(a1, bw[tap][0][1], acc[j][0], 0, 0, 0);
                acc[j][1] = __builtin_amdgcn_mfma_f32_16x16x32_bf16(a1, bw[tap][1][1], acc[j][1], 0, 0, 0);
            }
        }
    }

    const int f0 = nh * 32 + lm;
    const int hrow = h0 + r;
#pragma unroll
    for (int j = 0; j < 2; ++j) {
        const int mt = mh * 2 + j;
        if (mt < MTN) {
#pragma unroll
            for (int ntl = 0; ntl < 2; ++ntl) {
                const f32x4 v = acc[j][ntl];
                const float bb = ntl ? b1 : b0;
                float4 s;
                s.x = v[0] + bb; s.y = v[1] + bb; s.z = v[2] + bb; s.w = v[3] + bb;
                *(float4*)(out + ((n * COUT + f0 + ntl * 16) * HH + hrow) * WW
                           + c0 + mt * 16 + q * 4) = s;
            }
        }
    }
}

__global__ __launch_bounds__(512, 2)
void conv3x3_mfma(const float* __restrict__ x, const short* __restrict__ wbf,
                  const float* __restrict__ bias, float* __restrict__ out)
{
    __shared__ __align__(16) short lds[LDS_SHORTS];
    const int tid = threadIdx.x;
    const int n = blockIdx.x;
    const int ws = blockIdx.y;          // 0: out cols 0..63; 1: cols 64..111
    const int hb = blockIdx.z * 14;     // 14-row strip = 3 pairs + 1 tail tile

    const int MTN   = ws ? 3 : 4;
    const int W4N   = ws ? 12 : 16;
    const int c0    = ws * 64;
    const int padw  = ws ? 49 : 0;
    const int gce   = ws ? 63 : 64;
    const int wedge = ws ? 0 : 65;

    const int wave = tid >> 6;         // 0..7
    const int r  = wave >> 2;          // output row within tile (0..1)
    const int nh = (wave >> 1) & 1;    // cout half
    const int mh = wave & 1;           // mt half
    const int lane = tid & 63;
    const int lm = lane & 15;
    const int q  = lane >> 4;

    StageRegs sr;

    // ---- prologue: write rows hb-1..hb+4; leave hb+5..hb+8 loads in flight ----
    stage_load (x,  tid, n, c0, W4N, gce,  hb - 1, 4, sr);
    stage_write(lds, tid, W4N, padw, wedge, hb - 1, 4, sr);
    stage_load (x,  tid, n, c0, W4N, gce,  hb + 3, 2, sr);
    stage_write(lds, tid, W4N, padw, wedge, hb + 3, 2, sr);
    stage_load (x,  tid, n, c0, W4N, gce,  hb + 5, 4, sr);

    // ---- B preload: 36 frags (144 VGPR) + identity-asm pin (no remat/reload) ----
    bf16x8 bw[9][2][2];
#pragma unroll
    for (int t = 0; t < 9; ++t)
#pragma unroll
        for (int ntl = 0; ntl < 2; ++ntl) {
            const int f = nh * 32 + ntl * 16 + lm;
            bw[t][ntl][0] = *(const bf16x8*)(wbf + (t * 8 + q) * 512 + f * 8);
            bw[t][ntl][1] = *(const bf16x8*)(wbf + (t * 8 + 4 + q) * 512 + f * 8);
        }
#pragma unroll
    for (int t = 0; t < 9; ++t)
#pragma unroll
        for (int ntl = 0; ntl < 2; ++ntl)
#pragma unroll
            for (int cb = 0; cb < 2; ++cb)
                asm volatile("" : "=v"(bw[t][ntl][cb]) : "0"(bw[t][ntl][cb]));

    const int f0 = nh * 32 + lm;
    const float b0 = bias[f0];
    const float b1 = bias[f0 + 16];

    BAR_LGKM();

    // ---- 3 pairs: [tileA | W(oh+5) L(next) | tileB | barrier] ----
    // Ring safety: pair reads rows oh-1..oh+4, writes oh+5..oh+8 -> the 10 live
    // rows are consecutive -> all distinct mod 10; no intra-pair barrier needed.
#pragma unroll 1
    for (int p = 0; p < 3; ++p) {
        const int oh = hb + 4 * p;
        tile_compute(lds, bw, out, n, c0, MTN, oh, r, nh, mh, lm, q, b0, b1);
        stage_write(lds, tid, W4N, padw, wedge, oh + 5, (p == 2) ? 2 : 4, sr);
        if (p == 0)      stage_load(x, tid, n, c0, W4N, gce, oh + 9, 4, sr);
        else if (p == 1) stage_load(x, tid, n, c0, W4N, gce, oh + 9, 2, sr);
        tile_compute(lds, bw, out, n, c0, MTN, oh + 2, r, nh, mh, lm, q, b0, b1);
        BAR_LGKM();
    }
    // ---- tail tile (rows hb+12, hb+13) ----
    tile_compute(lds, bw, out, n, c0, MTN, hb + 12, r, nh, mh, lm, q, b0, b1);
}

extern "C" void kernel_launch(void* const* d_in, const int* in_sizes, int n_in,
                              void* d_out, int out_size, void* d_ws, size_t ws_size,
                              hipStream_t stream) {
    const float* x = (const float*)d_in[0];
    const float* w = (const float*)d_in[1];
    const float* b = (const float*)d_in[2];
    float* out = (float*)d_out;
    short* wbf = (short*)d_ws;   // 36864 shorts = 73728 B

    conv_wprep<<<144, 256, 0, stream>>>(w, wbf);   // 144*256 == 36864 exactly
    // grid: 256 blocks = 1/CU, 8 waves (2/SIMD). linear id % 8 == n % 8 keeps
    // each image's strip blocks on one XCD for halo-row L2 reuse.
    dim3 grid(16, 2, 8);
    conv3x3_mfma<<<grid, 512, 0, stream>>>(x, wbf, b, out);
}